// Round 5
// baseline (301.963 us; speedup 1.0000x reference)
//
#include <hip/hip_runtime.h>
#include <math.h>

#define N_NODES 16384
#define IN_DIM  512
#define HID_DIM 256
#define OUT_DIM 128
#define MAXDEG  128

typedef float f4v __attribute__((ext_vector_type(4)));

__device__ __forceinline__ float bf2f(unsigned short u) {
    return __uint_as_float(((unsigned int)u) << 16);
}
__device__ __forceinline__ unsigned short f2bf(float f) {
    unsigned int u = __float_as_uint(f);
    return (unsigned short)((u + 0x7FFFu + ((u >> 16) & 1u)) >> 16);
}

// ---------------------------------------------------------------------------
// 64x64 f32 GEMM tile (h1 = x @ W1, bf16 out). 256 threads, 4x4 micro-tile,
// K-chunk 16, As transposed [k][m] so fragments are ds_read_b128.
// ---------------------------------------------------------------------------
__device__ __forceinline__ void gemm_tile_bf16out(
    const float* __restrict__ Amat, const float* __restrict__ B,
    unsigned short* __restrict__ C, int K, int N, int m0, int n0,
    float (*As)[68], float (*Bs)[64]) {
    const int t  = threadIdx.x;
    const int tx = t & 15, ty = t >> 4;
    float acc[4][4] = {};
    for (int kt = 0; kt < K; kt += 16) {
        {
            const int m = t >> 2, k4 = (t & 3) * 4;
            const float4 v = *(const float4*)(Amat + (size_t)(m0 + m) * K + kt + k4);
            As[k4 + 0][m] = v.x; As[k4 + 1][m] = v.y;
            As[k4 + 2][m] = v.z; As[k4 + 3][m] = v.w;
        }
        {
            const int k = t >> 4, c4 = (t & 15) * 4;
            *(float4*)&Bs[k][c4] = *(const float4*)(B + (size_t)(kt + k) * N + n0 + c4);
        }
        __syncthreads();
        #pragma unroll
        for (int k = 0; k < 16; ++k) {
            const float4 a = *(const float4*)&As[k][ty * 4];
            const float4 b = *(const float4*)&Bs[k][tx * 4];
            const float av[4] = {a.x, a.y, a.z, a.w};
            const float bv[4] = {b.x, b.y, b.z, b.w};
            #pragma unroll
            for (int i = 0; i < 4; ++i)
                #pragma unroll
                for (int j = 0; j < 4; ++j)
                    acc[i][j] += av[i] * bv[j];
        }
        __syncthreads();
    }
    #pragma unroll
    for (int i = 0; i < 4; ++i) {
        const size_t off = (size_t)(m0 + ty * 4 + i) * N + n0 + tx * 4;
        ushort4 o;
        o.x = f2bf(acc[i][0]); o.y = f2bf(acc[i][1]);
        o.z = f2bf(acc[i][2]); o.w = f2bf(acc[i][3]);
        *(ushort4*)(C + off) = o;
    }
}

// ---------------------------------------------------------------------------
// Fused: blocks 0..1023 = 64x64 tiles of h1 = x @ W1 (start in the FIRST
// dispatch round -> no GEMM tail past the scan); blocks 1024..5119 scan the
// 1.07 GB adjacency (4 rows/block, wave/row, nontemporal loads, 2-chunk
// unroll) building adj lists + deg^-1/2.
// ---------------------------------------------------------------------------
__global__ __launch_bounds__(256) void scan_gemm_kernel(
    const float* __restrict__ A,
    int* __restrict__ adj, int* __restrict__ cnt, float* __restrict__ din,
    const float* __restrict__ X, const float* __restrict__ W1,
    unsigned short* __restrict__ H1) {
    __shared__ float As[16][68];
    __shared__ float Bs[16][64];
    const int bid = blockIdx.x;
    if (bid < 1024) {
        const int n0 = (bid & 3) * 64;
        const int m0 = (bid >> 2) * 64;
        gemm_tile_bf16out(X, W1, H1, IN_DIM, HID_DIM, m0, n0, As, Bs);
        return;
    }
    const int s    = bid - 1024;           // 0..4095
    const int lane = threadIdx.x & 63;
    const int row  = s * 4 + (threadIdx.x >> 6);
    const f4v* arow = (const f4v*)(A + (size_t)row * N_NODES);
    const unsigned long long lt = (1ull << lane) - 1ull;
    int base = 0;
    for (int chunk = 0; chunk < N_NODES / 256; chunk += 2) {
        const f4v v0 = __builtin_nontemporal_load(&arow[chunk * 64 + lane]);
        const f4v v1 = __builtin_nontemporal_load(&arow[chunk * 64 + 64 + lane]);
        const float vv[8] = {v0.x, v0.y, v0.z, v0.w, v1.x, v1.y, v1.z, v1.w};
        #pragma unroll
        for (int h = 0; h < 2; ++h) {
            const int c0 = (chunk + h) * 256 + lane * 4;
            #pragma unroll
            for (int i = 0; i < 4; ++i) {
                const bool nz = vv[h * 4 + i] != 0.f;
                const unsigned long long m = __ballot(nz);
                if (nz) {
                    const int p = base + __popcll(m & lt);
                    if (p < MAXDEG) adj[row * MAXDEG + p] = c0 + i;
                }
                base += __popcll(m);
            }
        }
    }
    if (lane == 0) {
        cnt[row] = base < MAXDEG ? base : MAXDEG;
        din[row] = base > 0 ? 1.0f / sqrtf((float)base) : 0.0f;
    }
}

// ---------------------------------------------------------------------------
// Fused agg1 + matvec: per node (one wave, 8 nodes/wave sequentially):
//   z1 = l2norm(elu(din*sum_e h1[e]*din[e] + b1))   -> f32 out
//   h2 = bf16(z1 @ W2)                              -> bf16 ws
// W2 staged once per block in LDS as bf16 pairs: W2s[k*64+j] holds
// {W2[k][2j], W2[k][2j+1]}; lane j reads bank j%32 -> 2-way alias (free).
// z1 row staged in LDS per wave -> broadcast reads for the matvec.
// LDS = 64K + 4K + 2K + 2K = 72KB -> 2 blocks/CU, 512 blocks all resident.
// ---------------------------------------------------------------------------
__global__ __launch_bounds__(256) void agg1_mv_kernel(
    const unsigned short* __restrict__ h1, const int* __restrict__ adj,
    const int* __restrict__ cnt, const float* __restrict__ din,
    const float* __restrict__ b1, const float* __restrict__ W2,
    float* __restrict__ z1, unsigned short* __restrict__ h2) {
    __shared__ unsigned int W2s[HID_DIM * 64];   // 64 KB
    __shared__ float z1s[4][HID_DIM];            // 4 KB
    __shared__ int   s_adj[4][MAXDEG];           // 2 KB
    __shared__ float s_dsc[4][MAXDEG];           // 2 KB
    const int tid = threadIdx.x;
    for (int idx = tid; idx < HID_DIM * 64; idx += 256) {
        const int k = idx >> 6, j2 = idx & 63;
        const float2 w = *(const float2*)(W2 + k * OUT_DIM + j2 * 2);
        W2s[idx] = ((unsigned int)f2bf(w.y) << 16) | (unsigned int)f2bf(w.x);
    }
    __syncthreads();
    const int wid  = tid >> 6;
    const int lane = tid & 63;
    const int c0   = lane * 4;
    for (int it = 0; it < 8; ++it) {
        const int node = (blockIdx.x * 4 + wid) * 8 + it;
        const int n    = cnt[node];
        for (int e = lane; e < n; e += 64) {
            const int src = adj[node * MAXDEG + e];
            s_adj[wid][e] = src;
            s_dsc[wid][e] = din[src];
        }
        float acc[4] = {};
        #define GATHER(idx_)                                                   \
            do {                                                               \
                const int ei_ = (idx_);                                        \
                const ushort4 hv_ = *(const ushort4*)(                         \
                    h1 + (size_t)s_adj[wid][ei_] * HID_DIM + c0);              \
                const float w_ = s_dsc[wid][ei_];                              \
                acc[0] += bf2f(hv_.x) * w_; acc[1] += bf2f(hv_.y) * w_;        \
                acc[2] += bf2f(hv_.z) * w_; acc[3] += bf2f(hv_.w) * w_;        \
            } while (0)
        int e = 0;
        for (; e + 8 <= n; e += 8) {
            #pragma unroll
            for (int uu = 0; uu < 8; ++uu) GATHER(e + uu);
        }
        for (; e < n; ++e) GATHER(e);
        #undef GATHER
        const float dn = din[node];
        float val[4];
        float ss = 0.f;
        #pragma unroll
        for (int u = 0; u < 4; ++u) {
            float v = acc[u] * dn + b1[c0 + u];
            v = v > 0.f ? v : expm1f(v);
            val[u] = v;
            ss += v * v;
        }
        #pragma unroll
        for (int off = 32; off > 0; off >>= 1) ss += __shfl_xor(ss, off, 64);
        const float inv = 1.0f / fmaxf(sqrtf(ss), 1e-12f);
        #pragma unroll
        for (int u = 0; u < 4; ++u) val[u] *= inv;
        *(float4*)(z1 + (size_t)node * HID_DIM + c0) =
            make_float4(val[0], val[1], val[2], val[3]);
        *(float4*)&z1s[wid][c0] = make_float4(val[0], val[1], val[2], val[3]);
        // matvec: lane j computes h2[node][2j], h2[node][2j+1]
        float h0 = 0.f, h1v = 0.f;
        #pragma unroll 8
        for (int k4 = 0; k4 < HID_DIM / 4; ++k4) {
            const float4 zv = *(const float4*)&z1s[wid][k4 * 4];
            const float zarr[4] = {zv.x, zv.y, zv.z, zv.w};
            #pragma unroll
            for (int kk = 0; kk < 4; ++kk) {
                const unsigned int w = W2s[(k4 * 4 + kk) * 64 + lane];
                h0  += zarr[kk] * __uint_as_float(w << 16);
                h1v += zarr[kk] * __uint_as_float(w & 0xffff0000u);
            }
        }
        ushort2 o;
        o.x = f2bf(h0);
        o.y = f2bf(h1v);
        *(ushort2*)(h2 + (size_t)node * OUT_DIM + lane * 2) = o;
    }
}

// ---------------------------------------------------------------------------
// agg2: 4 nodes/block (wave per node), bf16 gathers, f32 out with L2-norm.
// ---------------------------------------------------------------------------
__global__ __launch_bounds__(256) void agg2_kernel(
    const unsigned short* __restrict__ h, const int* __restrict__ adj,
    const int* __restrict__ cnt, const float* __restrict__ din,
    const float* __restrict__ bias, float* __restrict__ out) {
    __shared__ int   s_adj[4][MAXDEG];
    __shared__ float s_dsc[4][MAXDEG];
    const int wid  = threadIdx.x >> 6;
    const int lane = threadIdx.x & 63;
    const int node = blockIdx.x * 4 + wid;
    const int n    = cnt[node];
    for (int e = lane; e < n; e += 64) {
        const int src = adj[node * MAXDEG + e];
        s_adj[wid][e] = src;
        s_dsc[wid][e] = din[src];
    }
    __syncthreads();
    const int c0 = lane * 2;
    float acc[2] = {};
    #define GATHER(idx_)                                                       \
        do {                                                                   \
            const int ei_ = (idx_);                                            \
            const ushort2 hv_ = *(const ushort2*)(                             \
                h + (size_t)s_adj[wid][ei_] * OUT_DIM + c0);                   \
            const float w_ = s_dsc[wid][ei_];                                  \
            acc[0] += bf2f(hv_.x) * w_; acc[1] += bf2f(hv_.y) * w_;            \
        } while (0)
    int e = 0;
    for (; e + 8 <= n; e += 8) {
        #pragma unroll
        for (int uu = 0; uu < 8; ++uu) GATHER(e + uu);
    }
    for (; e < n; ++e) GATHER(e);
    #undef GATHER
    const float dn = din[node];
    float val[2];
    float ss = 0.f;
    #pragma unroll
    for (int u = 0; u < 2; ++u) {
        float v = acc[u] * dn + bias[c0 + u];
        val[u] = v;
        ss += v * v;
    }
    #pragma unroll
    for (int off = 32; off > 0; off >>= 1) ss += __shfl_xor(ss, off, 64);
    const float inv = 1.0f / fmaxf(sqrtf(ss), 1e-12f);
    *(float2*)(out + (size_t)node * OUT_DIM + c0) =
        make_float2(val[0] * inv, val[1] * inv);
}

// ---------------------------------------------------------------------------
extern "C" void kernel_launch(void* const* d_in, const int* in_sizes, int n_in,
                              void* d_out, int out_size, void* d_ws, size_t ws_size,
                              hipStream_t stream) {
    const float* x  = (const float*)d_in[0];
    const float* A  = (const float*)d_in[1];
    const float* W1 = (const float*)d_in[2];
    const float* b1 = (const float*)d_in[3];
    const float* W2 = (const float*)d_in[4];
    const float* b2 = (const float*)d_in[5];

    float* out = (float*)d_out;
    float* z2  = out;                                   // 16384 x 128
    float* z1  = out + (size_t)N_NODES * OUT_DIM;       // 16384 x 256

    char* p = (char*)d_ws;
    int*   adj = (int*)p;            p += (size_t)N_NODES * MAXDEG * sizeof(int);
    int*   cnt = (int*)p;            p += (size_t)N_NODES * sizeof(int);
    float* din = (float*)p;          p += (size_t)N_NODES * sizeof(float);
    unsigned short* h1 = (unsigned short*)p;
    p += (size_t)N_NODES * HID_DIM * sizeof(unsigned short);
    unsigned short* h2 = (unsigned short*)p;

    // 1) [A-scan || h1 = bf16(x @ W1)] fused; GEMM blocks first (no tail)
    scan_gemm_kernel<<<5120, 256, 0, stream>>>(A, adj, cnt, din, x, W1, h1);

    // 2) z1 = l2norm(elu(agg(h1*din)*din + b1)) -> f32; h2 = bf16(z1 @ W2)
    agg1_mv_kernel<<<512, 256, 0, stream>>>(h1, adj, cnt, din, b1, W2, z1, h2);

    // 3) z2 = l2norm(agg(h2*din)*din + b2) -> f32
    agg2_kernel<<<N_NODES / 4, 256, 0, stream>>>(h2, adj, cnt, din, b2, z2);
}